// Round 6
// baseline (1151.786 us; speedup 1.0000x reference)
//
#include <hip/hip_runtime.h>

typedef unsigned short ushort_t;
typedef unsigned int uint_t;

typedef __bf16 bf16x8 __attribute__((ext_vector_type(8)));
typedef float  floatx4 __attribute__((ext_vector_type(4)));

#define AS3 __attribute__((address_space(3)))
#define AS1 __attribute__((address_space(1)))

// ---------------- dims ----------------
#define BATCH 512
#define D_IN  120000
#define N1P   640   // 600 padded to 5*128
#define N2P   640
#define N3P   320
#define N4P   256
#define N5P   256

// gemm1 split-K: 50 chunks of 2400 (75 iters of BK=32); grid 1000 = 8 XCDs * 125
#define KSPLIT 50
#define KCHUNK 2400

// ---------------- layer-1 partition params ----------------
#define HALF    60000
#define CHW     15000          // build accumulator width (4 phases per half)
#define NREG    1200
#define NB      256            // partition blocks
#define RSTRIDE 6912           // slab slots per region: mean 6000, +11 sigma

// ---------------- workspace layout ----------------
static constexpr long O_W1 = 0;                          // bf16 [640][120000]
static constexpr long SZ_W1 = 640L * 120000 * 2;
static constexpr long O_W2 = O_W1 + SZ_W1;               // f32 [640][640]
static constexpr long SZ_W2 = 640L * 640 * 4;
static constexpr long O_W3 = O_W2 + SZ_W2;               // f32 [320][640]
static constexpr long SZ_W3 = 320L * 640 * 4;
static constexpr long O_W4 = O_W3 + SZ_W3;               // f32 [256][320]
static constexpr long SZ_W4 = 256L * 320 * 4;
static constexpr long O_W5 = O_W4 + SZ_W4;               // f32 [256][256]
static constexpr long SZ_W5 = 256L * 256 * 4;
static constexpr long O_Y1 = O_W5 + SZ_W5;               // f32 [512][640] split-K target
static constexpr long SZ_Y1 = 512L * 640 * 4;
static constexpr long ZERO_OFF = O_W2;                   // zero W2..W5 + y1
static constexpr long ZERO_BYTES = (O_Y1 + SZ_Y1) - O_W2;
static constexpr long O_XB = O_Y1 + SZ_Y1;               // bf16 [512][120000]
static constexpr long SZ_XB = 512L * 120000 * 2;         // 122,880,000
// partition arrays alias Xb (live only until build_w1; cast runs after and overwrites)
static constexpr long O_CNT = O_XB;                          // int [NREG][NB]
static constexpr long O_OFF = O_CNT + (long)NREG * NB * 4;   // int [NB][NREG]
static constexpr long O_TOT = O_OFF + (long)NB * NREG * 4;   // int [NREG]
static constexpr long O_REC = O_TOT + 4800;                  // int2 [NREG][RSTRIDE] = 66.4 MB
// h-buffers alias Xb (Xb is dead once gemm1 completes)
static constexpr long O_H2 = O_XB;                       // f32 [512][640]
static constexpr long O_Y3 = O_H2 + 512L * 640 * 4;      // f32 [512][320]
static constexpr long O_Y4 = O_Y3 + 512L * 320 * 4;      // f32 [512][256]
// total ws requirement = O_XB + SZ_XB = 280,838,144 bytes (same as R5)

// ---------------- helpers ----------------
__device__ __forceinline__ ushort_t f2bf(float f) {
    union { float f; uint_t u; } x;
    x.f = f;
    uint_t u = x.u;
    return (ushort_t)((u + 0x7FFFu + ((u >> 16) & 1u)) >> 16);  // RNE
}
__device__ __forceinline__ float silu_f(float z) {
    return z / (1.f + expf(-z));
}
__device__ __forceinline__ void load16_lds(const void* g, void* l) {
    __builtin_amdgcn_global_load_lds((const AS1 char*)g, (AS3 char*)l, 16, 0, 0);
}

// ---------------- zero workspace (small region only) ----------------
__global__ void zero_f4(float4* __restrict__ p, long n4) {
    long stride = (long)gridDim.x * blockDim.x;
    for (long i = (long)blockIdx.x * blockDim.x + threadIdx.x; i < n4; i += stride)
        p[i] = make_float4(0.f, 0.f, 0.f, 0.f);
}

// ---------------- cast x: fp32 -> bf16, 8 elems/thread ----------------
__global__ void cast_f32_bf16(const float* __restrict__ X, ushort_t* __restrict__ Xb, long n8) {
    long t = (long)blockIdx.x * blockDim.x + threadIdx.x;
    if (t >= n8) return;
    const float4* p = (const float4*)X + 2 * t;
    float4 a = p[0], b = p[1];
    union { ushort_t us[8]; uint4 v; } u;
    u.us[0] = f2bf(a.x); u.us[1] = f2bf(a.y); u.us[2] = f2bf(a.z); u.us[3] = f2bf(a.w);
    u.us[4] = f2bf(b.x); u.us[5] = f2bf(b.y); u.us[6] = f2bf(b.z); u.us[7] = f2bf(b.w);
    ((uint4*)Xb)[t] = u.v;
}

// ---------------- layer-1 pass A: per-block region histogram (LDS only) ----------------
__global__ __launch_bounds__(512) void hist1(const int* __restrict__ idx, int nnz, int chunk,
                                             int* __restrict__ counts /*[NREG][NB]*/) {
    __shared__ uint_t h[NREG];
    const int b = blockIdx.x, t = threadIdx.x;
    for (int i = t; i < NREG; i += 512) h[i] = 0;
    __syncthreads();
    const int s = b * chunk;
    const int e = min(s + chunk, nnz);
    for (int i = s + t; i < e; i += 512) {
        int r = idx[i];
        int c = idx[nnz + i];
        atomicAdd(&h[r * 2 + (c >= HALF ? 1 : 0)], 1u);
    }
    __syncthreads();
    for (int i = t; i < NREG; i += 512) counts[(long)i * NB + b] = (int)h[i];
}

// ---------------- layer-1 pass B: per-region exclusive scan over block counts ----------------
__global__ __launch_bounds__(NB) void scan1(const int* __restrict__ counts /*[NREG][NB]*/,
                                            int* __restrict__ offs /*[NB][NREG]*/,
                                            int* __restrict__ totals) {
    __shared__ int s[NB];
    const int reg = blockIdx.x, t = threadIdx.x;
    const int v = counts[(long)reg * NB + t];
    s[t] = v;
    __syncthreads();
    for (int o = 1; o < NB; o <<= 1) {
        int x = (t >= o) ? s[t - o] : 0;
        __syncthreads();
        s[t] += x;
        __syncthreads();
    }
    offs[(long)t * NREG + reg] = s[t] - v;  // exclusive prefix
    if (t == NB - 1) totals[reg] = s[t];
}

// ---------------- layer-1 pass C: scatter records into block-private spans ----------------
__global__ __launch_bounds__(512) void scatter1(const int* __restrict__ idx,
                                                const float* __restrict__ vals,
                                                int nnz, int chunk,
                                                const int* __restrict__ offs /*[NB][NREG]*/,
                                                int2* __restrict__ rec) {
    __shared__ int cur[NREG];
    const int b = blockIdx.x, t = threadIdx.x;
    const int* ob = offs + (long)b * NREG;
    for (int i = t; i < NREG; i += 512) cur[i] = i * RSTRIDE + ob[i];
    __syncthreads();
    const int s = b * chunk;
    const int e = min(s + chunk, nnz);
    for (int i = s + t; i < e; i += 512) {
        int r = idx[i];
        int c = idx[nnz + i];
        float v = vals[i];
        int h = (c >= HALF) ? 1 : 0;
        int reg = r * 2 + h;
        int slot = atomicAdd(&cur[reg], 1);  // LDS atomic -> private global slot
        if (slot < (reg + 1) * RSTRIDE)
            rec[slot] = make_int2(c - h * HALF, __float_as_int(v));
    }
}

// ---------------- layer-1 pass D: LDS f32 accumulate, single bf16 writeout ----------------
__global__ __launch_bounds__(512) void build_w1(const int2* __restrict__ rec,
                                                const int* __restrict__ totals,
                                                ushort_t* __restrict__ W) {
    const int bid = blockIdx.x;
    const int r = bid >> 1, h = bid & 1;
    const int t = threadIdx.x;
    ushort_t* dstbase = W + (size_t)r * D_IN + h * HALF;

    if (r >= 600) {  // padding rows: stream zeros
        uint4 z = make_uint4(0, 0, 0, 0);
        for (int j = t * 8; j < HALF; j += 512 * 8) *(uint4*)(dstbase + j) = z;
        return;
    }

    __shared__ int2 lrec[RSTRIDE];  // 55,296 B
    __shared__ float acc[CHW];      // 60,000 B

    const int reg = r * 2 + h;
    const int n = min(totals[reg], RSTRIDE);
    const int2* src = rec + (long)reg * RSTRIDE;
    for (int i = t; i < n; i += 512) lrec[i] = src[i];
    __syncthreads();

#pragma unroll
    for (int ch = 0; ch < 4; ch++) {
        for (int j = t * 4; j < CHW; j += 512 * 4)
            *(float4*)&acc[j] = make_float4(0.f, 0.f, 0.f, 0.f);
        __syncthreads();
        const int base = ch * CHW;
        for (int i = t; i < n; i += 512) {
            int2 e = lrec[i];
            unsigned off = (unsigned)(e.x - base);
            if (off < (unsigned)CHW)
                atomicAdd(&acc[off], __int_as_float(e.y));  // ds_add_f32
        }
        __syncthreads();
        ushort_t* dst = dstbase + base;
        for (int j = t * 8; j < CHW; j += 512 * 8) {
            union { ushort_t us[8]; uint4 v; } u;
#pragma unroll
            for (int k = 0; k < 8; k++) u.us[k] = f2bf(acc[j + k]);
            *(uint4*)(dst + j) = u.v;
        }
        __syncthreads();
    }
}

// ---------------- merged scatter for W2..W5 (one launch) ----------------
__global__ void scatter_all(const int* __restrict__ i2, const float* __restrict__ v2, int n2,
                            const int* __restrict__ i3, const float* __restrict__ v3, int n3,
                            const int* __restrict__ i4, const float* __restrict__ v4, int n4,
                            const int* __restrict__ i5, const float* __restrict__ v5, int n5,
                            float* __restrict__ W2, float* __restrict__ W3,
                            float* __restrict__ W4, float* __restrict__ W5) {
    int i = blockIdx.x * blockDim.x + threadIdx.x;
    if (i < n2) { atomicAdd(&W2[(size_t)i2[i] * 640 + i2[n2 + i]], v2[i]); return; }
    i -= n2;
    if (i < n3) { atomicAdd(&W3[(size_t)i3[i] * 640 + i3[n3 + i]], v3[i]); return; }
    i -= n3;
    if (i < n4) { atomicAdd(&W4[(size_t)i4[i] * 320 + i4[n4 + i]], v4[i]); return; }
    i -= n4;
    if (i < n5) { atomicAdd(&W5[(size_t)i5[i] * 256 + i5[n5 + i]], v5[i]); }
}

// ---------------- GEMM1: y1(512x640,f32) += Xb @ W1^T, counted-vmcnt 3-stage pipeline ----
// 1D grid 1000; XCD-aware decode (b%8 = XCD): each k-split's 20 blocks contiguous on one
// XCD (R5: FETCH 942->157 MB). NEW: depth-2 prefetch over 3 LDS buffers; per-iteration
// raw s_barrier with COUNTED s_waitcnt vmcnt(4) (never 0 in main loop) so 2 stages stay
// in flight across barriers (T3+T4). LDS 48 KB -> 3 blocks/CU. LDS 16B-slot XOR swizzle
// on the SOURCE address (R4/R5: 0 bank conflicts); LDS stays linear (rule #21).
__global__ __launch_bounds__(256) void gemm1(const ushort_t* __restrict__ X,
                                             const ushort_t* __restrict__ W,
                                             float* __restrict__ Y) {
    __shared__ ushort_t sA[3][4096];   // 3 x 8 KB
    __shared__ ushort_t sB[3][4096];

    const int b = blockIdx.x;
    const int wrk = (b & 7) * 125 + (b >> 3);   // contiguous per XCD
    const int ksIdx = wrk / 20;
    const int tile = wrk % 20;
    const int bm = tile / 5, bn = tile % 5;
    const int ks = ksIdx * KCHUNK;
    const int iters = KCHUNK / 32;  // 75

    const int t = threadIdx.x;
    const int lane = t & 63;
    const int w = t >> 6;
    const int wm = w >> 1, wn = w & 1;
    const int i16 = lane & 15;
    const int qk = lane >> 4;

    // staging: thread t owns chunks t and t+256; chunk c (16B at LDS byte c*16) holds
    // (row = c>>2, k-quad = (c&3)^((c>>3)&3)) -> source address carries the swizzle.
    const int row0 = t >> 2;
    const int kq = (t & 3) ^ ((t >> 3) & 3);

    const ushort_t* pa0 = X + (size_t)(bm * 128 + row0) * D_IN + ks + kq * 8;
    const ushort_t* pa1 = pa0 + (size_t)64 * D_IN;
    const ushort_t* pb0 = W + (size_t)(bn * 128 + row0) * D_IN + ks + kq * 8;
    const ushort_t* pb1 = pb0 + (size_t)64 * D_IN;

    int aoff[4], boff[4];
#pragma unroll
    for (int mi = 0; mi < 4; mi++) {
        int row = wm * 64 + mi * 16 + i16;
        aoff[mi] = row * 64 + ((qk ^ ((row >> 1) & 3)) * 16);
    }
#pragma unroll
    for (int ni = 0; ni < 4; ni++) {
        int row = wn * 64 + ni * 16 + i16;
        boff[ni] = row * 64 + ((qk ^ ((row >> 1) & 3)) * 16);
    }
    const char* sAb = (const char*)sA;
    const char* sBb = (const char*)sB;

#define STAGE1(s) do {                                   \
        load16_lds(pa0, &sA[s][(w * 64) * 8]);           \
        load16_lds(pa1, &sA[s][(256 + w * 64) * 8]);     \
        load16_lds(pb0, &sB[s][(w * 64) * 8]);           \
        load16_lds(pb1, &sB[s][(256 + w * 64) * 8]);     \
        pa0 += 32; pa1 += 32; pb0 += 32; pb1 += 32; } while (0)

    floatx4 acc[4][4] = {};

    // prologue: 2 stages in flight
    STAGE1(0);
    STAGE1(1);

    for (int it = 0; it < iters; ++it) {
        // counted wait: ensure stage(it) landed; keep newer stage(s) in flight
        if (it < iters - 1) {
            asm volatile("s_waitcnt vmcnt(4)" ::: "memory");
        } else {
            asm volatile("s_waitcnt vmcnt(0)" ::: "memory");
        }
        __builtin_amdgcn_s_barrier();        // all waves' stage(it) confirmed
        __builtin_amdgcn_sched_barrier(0);   // no motion across the barrier (rule #18)

        if (it + 2 < iters) {                // prefetch 2 ahead (buf (it+2)%3 readers done)
            const int ns = (it + 2) % 3;
            STAGE1(ns);
        }

        const int cb = it % 3;
        bf16x8 af[4], bfr[4];
#pragma unroll
        for (int mi = 0; mi < 4; mi++)
            af[mi] = *(const bf16x8*)(sAb + cb * 8192 + aoff[mi]);
#pragma unroll
        for (int ni = 0; ni < 4; ni++)
            bfr[ni] = *(const bf16x8*)(sBb + cb * 8192 + boff[ni]);
#pragma unroll
        for (int mi = 0; mi < 4; mi++)
#pragma unroll
            for (int ni = 0; ni < 4; ni++)
                acc[mi][ni] = __builtin_amdgcn_mfma_f32_16x16x32_bf16(af[mi], bfr[ni], acc[mi][ni], 0, 0, 0);
    }
#undef STAGE1

    // epilogue: split-K atomic accumulate (C/D: col = lane&15, row = (lane>>4)*4 + reg)
#pragma unroll
    for (int mi = 0; mi < 4; mi++) {
#pragma unroll
        for (int ni = 0; ni < 4; ni++) {
#pragma unroll
            for (int r = 0; r < 4; r++) {
                int row = bm * 128 + wm * 64 + mi * 16 + qk * 4 + r;
                int col = bn * 128 + wn * 64 + ni * 16 + i16;
                atomicAdd(&Y[(size_t)row * N1P + col], acc[mi][ni][r]);
            }
        }
    }
}

// ---------------- fused small GEMM: C(512 x N) = act(bn(A)) @ W^T + b ----------------
// FRONTBN: A is RAW pre-BN input; each block computes per-column BN stats in-block
// (redundant ~1-2 MB L2 read, ~3 us) then applies bn+silu on the fly while staging A.
// ACT: silu on output. GUARD: store only col < outN. Eliminates bn_silu kernels and
// the h1/h3/h4 round-trips.
template <int FRONTBN, int ACT, int GUARD>
__global__ __launch_bounds__(256) void fgemm(const float* __restrict__ A, int lda,
                                             const float* __restrict__ g,
                                             const float* __restrict__ be, int statN,
                                             const float* __restrict__ W, int ldw,
                                             const float* __restrict__ bias, int biasN,
                                             float* __restrict__ out, int ldo, int outN,
                                             int K) {
    __shared__ float sA[64][20];
    __shared__ float sB[64][20];
    __shared__ float scs[640], shs[640];
    const int t = threadIdx.x;
    const int m0 = blockIdx.x * 64, n0 = blockIdx.y * 64;
    const int ty = t >> 4, tx = t & 15;
    const int lm = t >> 2, lq = t & 3;

    if (FRONTBN) {
        for (int c = t; c < K; c += 256) {
            float s = 0.f, ss = 0.f;
#pragma unroll 8
            for (int r = 0; r < BATCH; ++r) {
                float v = A[(size_t)r * lda + c];   // coalesced across threads
                s += v;
                ss += v * v;
            }
            float mean = s * (1.f / 512.f);
            float var  = ss * (1.f / 512.f) - mean * mean;
            float sc = 0.f, sh = 0.f;
            if (c < statN) {
                sc = rsqrtf(var + 1e-5f) * g[c];
                sh = be[c] - mean * sc;
            }
            scs[c] = sc;
            shs[c] = sh;
        }
        __syncthreads();
    }

    float acc[4][4] = {};

    for (int kt = 0; kt < K; kt += 16) {
        __syncthreads();
        float4 av = *(const float4*)&A[(size_t)(m0 + lm) * lda + kt + lq * 4];
        float4 wv = *(const float4*)&W[(size_t)(n0 + lm) * ldw + kt + lq * 4];
        if (FRONTBN) {
            const int k0 = kt + lq * 4;
            av.x = silu_f(av.x * scs[k0 + 0] + shs[k0 + 0]);
            av.y = silu_f(av.y * scs[k0 + 1] + shs[k0 + 1]);
            av.z = silu_f(av.z * scs[k0 + 2] + shs[k0 + 2]);
            av.w = silu_f(av.w * scs[k0 + 3] + shs[k0 + 3]);
        }
        sA[lm][lq * 4 + 0] = av.x; sA[lm][lq * 4 + 1] = av.y;
        sA[lm][lq * 4 + 2] = av.z; sA[lm][lq * 4 + 3] = av.w;
        sB[lm][lq * 4 + 0] = wv.x; sB[lm][lq * 4 + 1] = wv.y;
        sB[lm][lq * 4 + 2] = wv.z; sB[lm][lq * 4 + 3] = wv.w;
        __syncthreads();
#pragma unroll
        for (int kg = 0; kg < 4; kg++) {
            float4 a4[4], b4[4];
#pragma unroll
            for (int i = 0; i < 4; i++) a4[i] = *(const float4*)&sA[ty * 4 + i][kg * 4];
#pragma unroll
            for (int j = 0; j < 4; j++) b4[j] = *(const float4*)&sB[tx * 4 + j][kg * 4];
#pragma unroll
            for (int i = 0; i < 4; i++)
#pragma unroll
                for (int j = 0; j < 4; j++)
                    acc[i][j] += a4[i].x * b4[j].x + a4[i].y * b4[j].y +
                                 a4[i].z * b4[j].z + a4[i].w * b4[j].w;
        }
    }

#pragma unroll
    for (int i = 0; i < 4; i++) {
#pragma unroll
        for (int j = 0; j < 4; j++) {
            int row = m0 + ty * 4 + i;
            int col = n0 + tx * 4 + j;
            float v = acc[i][j];
            if (bias != nullptr && col < biasN) v += bias[col];
            if (ACT == 1) v = silu_f(v);
            if (GUARD) {
                if (col < outN) out[(size_t)row * ldo + col] = v;
            } else {
                out[(size_t)row * ldo + col] = v;
            }
        }
    }
}

// ---------------- launch ----------------
extern "C" void kernel_launch(void* const* d_in, const int* in_sizes, int n_in,
                              void* d_out, int out_size, void* d_ws, size_t ws_size,
                              hipStream_t stream) {
    const float* x   = (const float*)d_in[0];
    const int* idx1 = (const int*)d_in[1];  const float* val1 = (const float*)d_in[2];
    const int* idx2 = (const int*)d_in[4];  const float* val2 = (const float*)d_in[5];
    const float* b2 = (const float*)d_in[6];
    const int* idx3 = (const int*)d_in[7];  const float* val3 = (const float*)d_in[8];
    const int* idx4 = (const int*)d_in[10]; const float* val4 = (const float*)d_in[11];
    const int* idx5 = (const int*)d_in[13]; const float* val5 = (const float*)d_in[14];
    const float* b5 = (const float*)d_in[15];
    const float* g1 = (const float*)d_in[16]; const float* be1 = (const float*)d_in[17];
    const float* g2 = (const float*)d_in[18]; const float* be2 = (const float*)d_in[19];
    const float* g3 = (const float*)d_in[20]; const float* be3 = (const float*)d_in[21];

    const int nnz1 = in_sizes[1] / 2;
    const int nnz2 = in_sizes[4] / 2;
    const int nnz3 = in_sizes[7] / 2;
    const int nnz4 = in_sizes[10] / 2;
    const int nnz5 = in_sizes[13] / 2;

    char* ws = (char*)d_ws;
    ushort_t* W1 = (ushort_t*)(ws + O_W1);
    float* W2 = (float*)(ws + O_W2);
    float* W3 = (float*)(ws + O_W3);
    float* W4 = (float*)(ws + O_W4);
    float* W5 = (float*)(ws + O_W5);
    float* y1 = (float*)(ws + O_Y1);
    int*   cnt = (int*)(ws + O_CNT);
    int*   off = (int*)(ws + O_OFF);
    int*   tot = (int*)(ws + O_TOT);
    int2*  rec = (int2*)(ws + O_REC);
    ushort_t* Xb = (ushort_t*)(ws + O_XB);
    float* h2 = (float*)(ws + O_H2);
    float* y3 = (float*)(ws + O_Y3);
    float* y4 = (float*)(ws + O_Y4);

    // 1) zero W2..W5 + y1 (4.4 MB; W1 not pre-zeroed)
    zero_f4<<<dim3((unsigned)(ZERO_BYTES / 16 / 256 + 1)), dim3(256), 0, stream>>>(
        (float4*)(ws + ZERO_OFF), ZERO_BYTES / 16);

    // 2) layer-1 partition: histogram -> scan -> block-private scatter -> build
    {
        const int chunk = (nnz1 + NB - 1) / NB;
        hist1<<<dim3(NB), dim3(512), 0, stream>>>(idx1, nnz1, chunk, cnt);
        scan1<<<dim3(NREG), dim3(NB), 0, stream>>>(cnt, off, tot);
        scatter1<<<dim3(NB), dim3(512), 0, stream>>>(idx1, val1, nnz1, chunk, off, rec);
        build_w1<<<dim3(640 * 2), dim3(512), 0, stream>>>(rec, tot, W1);
    }

    // 3) cast x -> bf16 (overwrites partition arrays; they are dead now)
    {
        long n8 = (long)BATCH * D_IN / 8;  // 7,680,000
        cast_f32_bf16<<<dim3((unsigned)((n8 + 255) / 256)), dim3(256), 0, stream>>>(x, Xb, n8);
    }

    // 4) densify small weights (one launch)
    {
        int ntot = nnz2 + nnz3 + nnz4 + nnz5;
        scatter_all<<<dim3((ntot + 255) / 256), dim3(256), 0, stream>>>(
            idx2, val2, nnz2, idx3, val3, nnz3, idx4, val4, nnz4, idx5, val5, nnz5,
            W2, W3, W4, W5);
    }

    // 5) layer 1: MFMA GEMM, split-K = 50, XCD-aware + counted-vmcnt pipeline
    gemm1<<<dim3(8 * 125), dim3(256), 0, stream>>>(Xb, W1, y1);

    // 6) layer 2: silu(bn1(y1) @ W2^T + b2) -> h2   (BN1 fused into A-staging)
    fgemm<1, 1, 0><<<dim3(8, N2P / 64), dim3(256), 0, stream>>>(
        y1, N1P, g1, be1, 600, W2, 640, b2, 600, h2, N2P, N2P, 640);

    // 7) layer 3: h2 @ W3^T -> y3 (raw; b3 cancels in BN2)
    fgemm<0, 0, 0><<<dim3(8, N3P / 64), dim3(256), 0, stream>>>(
        h2, N2P, nullptr, nullptr, 0, W3, 640, nullptr, 0, y3, N3P, N3P, 640);

    // 8) layer 4: silu(bn2(y3)) @ W4^T -> y4 (raw; b4 cancels in BN3)
    fgemm<1, 0, 0><<<dim3(8, N4P / 64), dim3(256), 0, stream>>>(
        y3, N3P, g2, be2, 300, W4, 320, nullptr, 0, y4, N4P, N4P, 320);

    // 9) layer 5: silu(bn3(y4)) @ W5^T + b5 -> d_out (fp32, compact 512x200)
    fgemm<1, 0, 1><<<dim3(8, N5P / 64), dim3(256), 0, stream>>>(
        y4, N4P, g3, be3, 200, W5, 256, b5, 200, (float*)d_out, 200, 200, 256);

    (void)n_in; (void)out_size; (void)ws_size;
}

// Round 7
// 1038.072 us; speedup vs baseline: 1.1095x; 1.1095x over previous
//
#include <hip/hip_runtime.h>

typedef unsigned short ushort_t;
typedef unsigned int uint_t;

typedef __bf16 bf16x8 __attribute__((ext_vector_type(8)));
typedef float  floatx4 __attribute__((ext_vector_type(4)));

#define AS3 __attribute__((address_space(3)))
#define AS1 __attribute__((address_space(1)))

// ---------------- dims ----------------
#define BATCH 512
#define D_IN  120000
#define N1P   640   // 600 padded to 5*128
#define N2P   640
#define N3P   320
#define N4P   256
#define N5P   256

// gemm1 split-K: 30 chunks of 4000 (125 iters of BK=32); grid 600 = 8 XCDs * 75
#define KSPLIT 30
#define KCHUNK 4000

// ---------------- layer-1 partition params ----------------
#define HALF    60000
#define CHW     15000          // build accumulator width (4 phases per half)
#define NREG    1200
#define NB      256            // partition blocks
#define RSTRIDE 6912           // slab slots per region: mean 6000, +11 sigma

// ---------------- workspace layout ----------------
static constexpr long O_W1 = 0;                          // bf16 [640][120000]
static constexpr long SZ_W1 = 640L * 120000 * 2;
static constexpr long O_W2 = O_W1 + SZ_W1;               // f32 [640][640]
static constexpr long SZ_W2 = 640L * 640 * 4;
static constexpr long O_W3 = O_W2 + SZ_W2;               // f32 [320][640]
static constexpr long SZ_W3 = 320L * 640 * 4;
static constexpr long O_W4 = O_W3 + SZ_W3;               // f32 [256][320]
static constexpr long SZ_W4 = 256L * 320 * 4;
static constexpr long O_W5 = O_W4 + SZ_W4;               // f32 [256][256]
static constexpr long SZ_W5 = 256L * 256 * 4;
static constexpr long O_Y1 = O_W5 + SZ_W5;               // f32 [512][640] split-K target
static constexpr long SZ_Y1 = 512L * 640 * 4;
static constexpr long ZERO_OFF = O_W2;                   // zero W2..W5 + y1
static constexpr long ZERO_BYTES = (O_Y1 + SZ_Y1) - O_W2;
static constexpr long O_XB = O_Y1 + SZ_Y1;               // bf16 [512][120000]
static constexpr long SZ_XB = 512L * 120000 * 2;         // 122,880,000
// partition arrays alias Xb (live only until build_w1; cast runs after and overwrites)
static constexpr long O_CNT = O_XB;                          // int [NREG][NB]
static constexpr long O_OFF = O_CNT + (long)NREG * NB * 4;   // int [NB][NREG]
static constexpr long O_TOT = O_OFF + (long)NB * NREG * 4;   // int [NREG]
static constexpr long O_REC = O_TOT + 4800;                  // int2 [NREG][RSTRIDE] = 66.4 MB
// h-buffers alias Xb (Xb is dead once gemm1 completes)
static constexpr long O_H1 = O_XB;                       // f32 [512][640]
static constexpr long O_H2 = O_H1 + 512L * 640 * 4;      // f32 [512][640]
static constexpr long O_Y3 = O_H2 + 512L * 640 * 4;      // f32 [512][320]
static constexpr long O_H3 = O_Y3 + 512L * 320 * 4;      // f32 [512][320]
static constexpr long O_Y4 = O_H3 + 512L * 320 * 4;      // f32 [512][256]
static constexpr long O_H4 = O_Y4 + 512L * 256 * 4;      // f32 [512][256]
// total ws requirement = O_XB + SZ_XB = 280,838,144 bytes

// ---------------- helpers ----------------
__device__ __forceinline__ ushort_t f2bf(float f) {
    union { float f; uint_t u; } x;
    x.f = f;
    uint_t u = x.u;
    return (ushort_t)((u + 0x7FFFu + ((u >> 16) & 1u)) >> 16);  // RNE
}
__device__ __forceinline__ float silu_f(float z) {
    return z / (1.f + expf(-z));
}
__device__ __forceinline__ void load16_lds(const void* g, void* l) {
    __builtin_amdgcn_global_load_lds((const AS1 char*)g, (AS3 char*)l, 16, 0, 0);
}

// ---------------- zero workspace (small region only) ----------------
__global__ void zero_f4(float4* __restrict__ p, long n4) {
    long stride = (long)gridDim.x * blockDim.x;
    for (long i = (long)blockIdx.x * blockDim.x + threadIdx.x; i < n4; i += stride)
        p[i] = make_float4(0.f, 0.f, 0.f, 0.f);
}

// ---------------- cast x: fp32 -> bf16, 8 elems/thread ----------------
__global__ void cast_f32_bf16(const float* __restrict__ X, ushort_t* __restrict__ Xb, long n8) {
    long t = (long)blockIdx.x * blockDim.x + threadIdx.x;
    if (t >= n8) return;
    const float4* p = (const float4*)X + 2 * t;
    float4 a = p[0], b = p[1];
    union { ushort_t us[8]; uint4 v; } u;
    u.us[0] = f2bf(a.x); u.us[1] = f2bf(a.y); u.us[2] = f2bf(a.z); u.us[3] = f2bf(a.w);
    u.us[4] = f2bf(b.x); u.us[5] = f2bf(b.y); u.us[6] = f2bf(b.z); u.us[7] = f2bf(b.w);
    ((uint4*)Xb)[t] = u.v;
}

// ---------------- layer-1 pass A: per-block region histogram (LDS only) ----------------
__global__ __launch_bounds__(512) void hist1(const int* __restrict__ idx, int nnz, int chunk,
                                             int* __restrict__ counts /*[NREG][NB]*/) {
    __shared__ uint_t h[NREG];
    const int b = blockIdx.x, t = threadIdx.x;
    for (int i = t; i < NREG; i += 512) h[i] = 0;
    __syncthreads();
    const int s = b * chunk;
    const int e = min(s + chunk, nnz);
    for (int i = s + t; i < e; i += 512) {
        int r = idx[i];
        int c = idx[nnz + i];
        atomicAdd(&h[r * 2 + (c >= HALF ? 1 : 0)], 1u);
    }
    __syncthreads();
    for (int i = t; i < NREG; i += 512) counts[(long)i * NB + b] = (int)h[i];
}

// ---------------- layer-1 pass B: per-region exclusive scan over block counts ----------------
__global__ __launch_bounds__(NB) void scan1(const int* __restrict__ counts /*[NREG][NB]*/,
                                            int* __restrict__ offs /*[NB][NREG]*/,
                                            int* __restrict__ totals) {
    __shared__ int s[NB];
    const int reg = blockIdx.x, t = threadIdx.x;
    const int v = counts[(long)reg * NB + t];
    s[t] = v;
    __syncthreads();
    for (int o = 1; o < NB; o <<= 1) {
        int x = (t >= o) ? s[t - o] : 0;
        __syncthreads();
        s[t] += x;
        __syncthreads();
    }
    offs[(long)t * NREG + reg] = s[t] - v;  // exclusive prefix
    if (t == NB - 1) totals[reg] = s[t];
}

// ---------------- layer-1 pass C: scatter records into block-private spans ----------------
__global__ __launch_bounds__(512) void scatter1(const int* __restrict__ idx,
                                                const float* __restrict__ vals,
                                                int nnz, int chunk,
                                                const int* __restrict__ offs /*[NB][NREG]*/,
                                                int2* __restrict__ rec) {
    __shared__ int cur[NREG];
    const int b = blockIdx.x, t = threadIdx.x;
    const int* ob = offs + (long)b * NREG;
    for (int i = t; i < NREG; i += 512) cur[i] = i * RSTRIDE + ob[i];
    __syncthreads();
    const int s = b * chunk;
    const int e = min(s + chunk, nnz);
    for (int i = s + t; i < e; i += 512) {
        int r = idx[i];
        int c = idx[nnz + i];
        float v = vals[i];
        int h = (c >= HALF) ? 1 : 0;
        int reg = r * 2 + h;
        int slot = atomicAdd(&cur[reg], 1);  // LDS atomic -> private global slot
        if (slot < (reg + 1) * RSTRIDE)
            rec[slot] = make_int2(c - h * HALF, __float_as_int(v));
    }
}

// ---------------- layer-1 pass D: LDS f32 accumulate, single bf16 writeout ----------------
__global__ __launch_bounds__(512) void build_w1(const int2* __restrict__ rec,
                                                const int* __restrict__ totals,
                                                ushort_t* __restrict__ W) {
    const int bid = blockIdx.x;
    const int r = bid >> 1, h = bid & 1;
    const int t = threadIdx.x;
    ushort_t* dstbase = W + (size_t)r * D_IN + h * HALF;

    if (r >= 600) {  // padding rows: stream zeros
        uint4 z = make_uint4(0, 0, 0, 0);
        for (int j = t * 8; j < HALF; j += 512 * 8) *(uint4*)(dstbase + j) = z;
        return;
    }

    __shared__ int2 lrec[RSTRIDE];  // 55,296 B
    __shared__ float acc[CHW];      // 60,000 B

    const int reg = r * 2 + h;
    const int n = min(totals[reg], RSTRIDE);
    const int2* src = rec + (long)reg * RSTRIDE;
    for (int i = t; i < n; i += 512) lrec[i] = src[i];
    __syncthreads();

#pragma unroll
    for (int ch = 0; ch < 4; ch++) {
        for (int j = t * 4; j < CHW; j += 512 * 4)
            *(float4*)&acc[j] = make_float4(0.f, 0.f, 0.f, 0.f);
        __syncthreads();
        const int base = ch * CHW;
        for (int i = t; i < n; i += 512) {
            int2 e = lrec[i];
            unsigned off = (unsigned)(e.x - base);
            if (off < (unsigned)CHW)
                atomicAdd(&acc[off], __int_as_float(e.y));  // ds_add_f32
        }
        __syncthreads();
        ushort_t* dst = dstbase + base;
        for (int j = t * 8; j < CHW; j += 512 * 8) {
            union { ushort_t us[8]; uint4 v; } u;
#pragma unroll
            for (int k = 0; k < 8; k++) u.us[k] = f2bf(acc[j + k]);
            *(uint4*)(dst + j) = u.v;
        }
        __syncthreads();
    }
}

// ---------------- merged scatter for W2..W5 (one launch) ----------------
__global__ void scatter_all(const int* __restrict__ i2, const float* __restrict__ v2, int n2,
                            const int* __restrict__ i3, const float* __restrict__ v3, int n3,
                            const int* __restrict__ i4, const float* __restrict__ v4, int n4,
                            const int* __restrict__ i5, const float* __restrict__ v5, int n5,
                            float* __restrict__ W2, float* __restrict__ W3,
                            float* __restrict__ W4, float* __restrict__ W5) {
    int i = blockIdx.x * blockDim.x + threadIdx.x;
    if (i < n2) { atomicAdd(&W2[(size_t)i2[i] * 640 + i2[n2 + i]], v2[i]); return; }
    i -= n2;
    if (i < n3) { atomicAdd(&W3[(size_t)i3[i] * 640 + i3[n3 + i]], v3[i]); return; }
    i -= n3;
    if (i < n4) { atomicAdd(&W4[(size_t)i4[i] * 320 + i4[n4 + i]], v4[i]); return; }
    i -= n4;
    if (i < n5) { atomicAdd(&W5[(size_t)i5[i] * 256 + i5[n5 + i]], v5[i]); }
}

// ---------------- GEMM1: y1(512x640,f32) += Xb @ W1^T, counted-vmcnt 3-stage pipeline ----
// 1D grid 600; XCD-aware decode (b%8 = XCD): each k-split's 20 blocks near-contiguous on
// one XCD (R5/R6: FETCH 157 MB). Depth-2 prefetch over 3 LDS buffers; per-iteration raw
// s_barrier with COUNTED s_waitcnt vmcnt(4) (never 0 in main loop). KSPLIT 30 (was 50):
// -40% split-K epilogue atomics, 125 iters/block amortization. LDS 48 KB -> 3 blocks/CU.
// LDS 16B-slot XOR swizzle on the SOURCE address (0 bank conflicts measured R4-R6).
__global__ __launch_bounds__(256) void gemm1(const ushort_t* __restrict__ X,
                                             const ushort_t* __restrict__ W,
                                             float* __restrict__ Y) {
    __shared__ ushort_t sA[3][4096];   // 3 x 8 KB
    __shared__ ushort_t sB[3][4096];

    const int b = blockIdx.x;
    const int wrk = (b & 7) * 75 + (b >> 3);    // contiguous per XCD (600 = 8*75)
    const int ksIdx = wrk / 20;
    const int tile = wrk % 20;
    const int bm = tile / 5, bn = tile % 5;
    const int ks = ksIdx * KCHUNK;
    const int iters = KCHUNK / 32;  // 125

    const int t = threadIdx.x;
    const int lane = t & 63;
    const int w = t >> 6;
    const int wm = w >> 1, wn = w & 1;
    const int i16 = lane & 15;
    const int qk = lane >> 4;

    // staging: thread t owns chunks t and t+256; chunk c (16B at LDS byte c*16) holds
    // (row = c>>2, k-quad = (c&3)^((c>>3)&3)) -> source address carries the swizzle.
    const int row0 = t >> 2;
    const int kq = (t & 3) ^ ((t >> 3) & 3);

    const ushort_t* pa0 = X + (size_t)(bm * 128 + row0) * D_IN + ks + kq * 8;
    const ushort_t* pa1 = pa0 + (size_t)64 * D_IN;
    const ushort_t* pb0 = W + (size_t)(bn * 128 + row0) * D_IN + ks + kq * 8;
    const ushort_t* pb1 = pb0 + (size_t)64 * D_IN;

    int aoff[4], boff[4];
#pragma unroll
    for (int mi = 0; mi < 4; mi++) {
        int row = wm * 64 + mi * 16 + i16;
        aoff[mi] = row * 64 + ((qk ^ ((row >> 1) & 3)) * 16);
    }
#pragma unroll
    for (int ni = 0; ni < 4; ni++) {
        int row = wn * 64 + ni * 16 + i16;
        boff[ni] = row * 64 + ((qk ^ ((row >> 1) & 3)) * 16);
    }
    const char* sAb = (const char*)sA;
    const char* sBb = (const char*)sB;

#define STAGE1(s) do {                                   \
        load16_lds(pa0, &sA[s][(w * 64) * 8]);           \
        load16_lds(pa1, &sA[s][(256 + w * 64) * 8]);     \
        load16_lds(pb0, &sB[s][(w * 64) * 8]);           \
        load16_lds(pb1, &sB[s][(256 + w * 64) * 8]);     \
        pa0 += 32; pa1 += 32; pb0 += 32; pb1 += 32; } while (0)

    floatx4 acc[4][4] = {};

    // prologue: 2 stages in flight
    STAGE1(0);
    STAGE1(1);

    for (int it = 0; it < iters; ++it) {
        // counted wait: ensure stage(it) landed; keep newer stage(s) in flight
        if (it < iters - 1) {
            asm volatile("s_waitcnt vmcnt(4)" ::: "memory");
        } else {
            asm volatile("s_waitcnt vmcnt(0)" ::: "memory");
        }
        __builtin_amdgcn_s_barrier();        // all waves' stage(it) confirmed
        __builtin_amdgcn_sched_barrier(0);   // no motion across the barrier (rule #18)

        if (it + 2 < iters) {                // prefetch 2 ahead (buf (it+2)%3 readers done)
            const int ns = (it + 2) % 3;
            STAGE1(ns);
        }

        const int cb = it % 3;
        bf16x8 af[4], bfr[4];
#pragma unroll
        for (int mi = 0; mi < 4; mi++)
            af[mi] = *(const bf16x8*)(sAb + cb * 8192 + aoff[mi]);
#pragma unroll
        for (int ni = 0; ni < 4; ni++)
            bfr[ni] = *(const bf16x8*)(sBb + cb * 8192 + boff[ni]);
#pragma unroll
        for (int mi = 0; mi < 4; mi++)
#pragma unroll
            for (int ni = 0; ni < 4; ni++)
                acc[mi][ni] = __builtin_amdgcn_mfma_f32_16x16x32_bf16(af[mi], bfr[ni], acc[mi][ni], 0, 0, 0);
    }
#undef STAGE1

    // epilogue: split-K atomic accumulate (C/D: col = lane&15, row = (lane>>4)*4 + reg)
#pragma unroll
    for (int mi = 0; mi < 4; mi++) {
#pragma unroll
        for (int ni = 0; ni < 4; ni++) {
#pragma unroll
            for (int r = 0; r < 4; r++) {
                int row = bm * 128 + wm * 64 + mi * 16 + qk * 4 + r;
                int col = bn * 128 + wn * 64 + ni * 16 + i16;
                atomicAdd(&Y[(size_t)row * N1P + col], acc[mi][ni][r]);
            }
        }
    }
}

// ---------------- BatchNorm (training, biased var) + SiLU, coalesced 64-col tiles --------
__global__ __launch_bounds__(512) void bn_silu(const float* __restrict__ Y, int ld, int realN,
                                               const float* __restrict__ g,
                                               const float* __restrict__ be,
                                               float* __restrict__ H) {
    const int t = threadIdx.x;
    const int sub = t >> 6;          // 0..7
    const int c = t & 63;
    const int col = blockIdx.x * 64 + c;

    float s = 0.f, ss = 0.f;
#pragma unroll 8
    for (int r = sub; r < BATCH; r += 8) {
        float v = Y[(size_t)r * ld + col];
        s += v;
        ss += v * v;
    }
    __shared__ float rs[8][64], rq[8][64], scs[64], shs[64];
    rs[sub][c] = s;
    rq[sub][c] = ss;
    __syncthreads();
    if (t < 64) {
        float S = 0.f, SS = 0.f;
#pragma unroll
        for (int k = 0; k < 8; k++) { S += rs[k][t]; SS += rq[k][t]; }
        float mean = S * (1.f / 512.f);
        float var  = SS * (1.f / 512.f) - mean * mean;
        int cc = blockIdx.x * 64 + t;
        float sc = 0.f, sh = 0.f;
        if (cc < realN) {
            sc = rsqrtf(var + 1e-5f) * g[cc];
            sh = be[cc] - mean * sc;
        }
        scs[t] = sc;
        shs[t] = sh;
    }
    __syncthreads();
    const float sc = scs[c], sh = shs[c];
#pragma unroll 8
    for (int r = sub; r < BATCH; r += 8) {
        float v = Y[(size_t)r * ld + col];
        H[(size_t)r * ld + col] = silu_f(v * sc + sh);  // pad cols -> silu(0)=0
    }
}

// ---------------- small fp32 GEMM: C(512 x N) = A(512 x K) @ W^T(N x K) ----------------
template <int ACT, int GUARD>
__global__ __launch_bounds__(256) void small_gemm(const float* __restrict__ A, int lda,
                                                  const float* __restrict__ W, int ldw,
                                                  const float* __restrict__ bias, int biasN,
                                                  float* __restrict__ out, int ldo, int outN,
                                                  int K) {
    __shared__ float sA[64][20];
    __shared__ float sB[64][20];
    const int t = threadIdx.x;
    const int m0 = blockIdx.x * 64, n0 = blockIdx.y * 64;
    const int ty = t >> 4, tx = t & 15;
    const int lm = t >> 2, lq = t & 3;
    float acc[4][4] = {};

    for (int kt = 0; kt < K; kt += 16) {
        __syncthreads();
        float4 av = *(const float4*)&A[(size_t)(m0 + lm) * lda + kt + lq * 4];
        float4 wv = *(const float4*)&W[(size_t)(n0 + lm) * ldw + kt + lq * 4];
        sA[lm][lq * 4 + 0] = av.x; sA[lm][lq * 4 + 1] = av.y;
        sA[lm][lq * 4 + 2] = av.z; sA[lm][lq * 4 + 3] = av.w;
        sB[lm][lq * 4 + 0] = wv.x; sB[lm][lq * 4 + 1] = wv.y;
        sB[lm][lq * 4 + 2] = wv.z; sB[lm][lq * 4 + 3] = wv.w;
        __syncthreads();
#pragma unroll
        for (int kg = 0; kg < 4; kg++) {
            float4 a4[4], b4[4];
#pragma unroll
            for (int i = 0; i < 4; i++) a4[i] = *(const float4*)&sA[ty * 4 + i][kg * 4];
#pragma unroll
            for (int j = 0; j < 4; j++) b4[j] = *(const float4*)&sB[tx * 4 + j][kg * 4];
#pragma unroll
            for (int i = 0; i < 4; i++)
#pragma unroll
                for (int j = 0; j < 4; j++)
                    acc[i][j] += a4[i].x * b4[j].x + a4[i].y * b4[j].y +
                                 a4[i].z * b4[j].z + a4[i].w * b4[j].w;
        }
    }

#pragma unroll
    for (int i = 0; i < 4; i++) {
#pragma unroll
        for (int j = 0; j < 4; j++) {
            int row = m0 + ty * 4 + i;
            int col = n0 + tx * 4 + j;
            float v = acc[i][j];
            if (bias != nullptr && col < biasN) v += bias[col];
            if (ACT == 1) v = silu_f(v);
            if (GUARD) {
                if (col < outN) out[(size_t)row * ldo + col] = v;
            } else {
                out[(size_t)row * ldo + col] = v;
            }
        }
    }
}

// ---------------- launch ----------------
extern "C" void kernel_launch(void* const* d_in, const int* in_sizes, int n_in,
                              void* d_out, int out_size, void* d_ws, size_t ws_size,
                              hipStream_t stream) {
    const float* x   = (const float*)d_in[0];
    const int* idx1 = (const int*)d_in[1];  const float* val1 = (const float*)d_in[2];
    const int* idx2 = (const int*)d_in[4];  const float* val2 = (const float*)d_in[5];
    const float* b2 = (const float*)d_in[6];
    const int* idx3 = (const int*)d_in[7];  const float* val3 = (const float*)d_in[8];
    const int* idx4 = (const int*)d_in[10]; const float* val4 = (const float*)d_in[11];
    const int* idx5 = (const int*)d_in[13]; const float* val5 = (const float*)d_in[14];
    const float* b5 = (const float*)d_in[15];
    const float* g1 = (const float*)d_in[16]; const float* be1 = (const float*)d_in[17];
    const float* g2 = (const float*)d_in[18]; const float* be2 = (const float*)d_in[19];
    const float* g3 = (const float*)d_in[20]; const float* be3 = (const float*)d_in[21];

    const int nnz1 = in_sizes[1] / 2;
    const int nnz2 = in_sizes[4] / 2;
    const int nnz3 = in_sizes[7] / 2;
    const int nnz4 = in_sizes[10] / 2;
    const int nnz5 = in_sizes[13] / 2;

    char* ws = (char*)d_ws;
    ushort_t* W1 = (ushort_t*)(ws + O_W1);
    float* W2 = (float*)(ws + O_W2);
    float* W3 = (float*)(ws + O_W3);
    float* W4 = (float*)(ws + O_W4);
    float* W5 = (float*)(ws + O_W5);
    float* y1 = (float*)(ws + O_Y1);
    int*   cnt = (int*)(ws + O_CNT);
    int*   off = (int*)(ws + O_OFF);
    int*   tot = (int*)(ws + O_TOT);
    int2*  rec = (int2*)(ws + O_REC);
    ushort_t* Xb = (ushort_t*)(ws + O_XB);
    float* h1 = (float*)(ws + O_H1);
    float* h2 = (float*)(ws + O_H2);
    float* y3 = (float*)(ws + O_Y3);
    float* h3 = (float*)(ws + O_H3);
    float* y4 = (float*)(ws + O_Y4);
    float* h4 = (float*)(ws + O_H4);

    // 1) zero W2..W5 + y1 (4.4 MB; W1 not pre-zeroed)
    zero_f4<<<dim3((unsigned)(ZERO_BYTES / 16 / 256 + 1)), dim3(256), 0, stream>>>(
        (float4*)(ws + ZERO_OFF), ZERO_BYTES / 16);

    // 2) layer-1 partition: histogram -> scan -> block-private scatter -> build
    {
        const int chunk = (nnz1 + NB - 1) / NB;
        hist1<<<dim3(NB), dim3(512), 0, stream>>>(idx1, nnz1, chunk, cnt);
        scan1<<<dim3(NREG), dim3(NB), 0, stream>>>(cnt, off, tot);
        scatter1<<<dim3(NB), dim3(512), 0, stream>>>(idx1, val1, nnz1, chunk, off, rec);
        build_w1<<<dim3(640 * 2), dim3(512), 0, stream>>>(rec, tot, W1);
    }

    // 3) cast x -> bf16 (overwrites partition arrays; they are dead now)
    {
        long n8 = (long)BATCH * D_IN / 8;  // 7,680,000
        cast_f32_bf16<<<dim3((unsigned)((n8 + 255) / 256)), dim3(256), 0, stream>>>(x, Xb, n8);
    }

    // 4) densify small weights (one launch)
    {
        int ntot = nnz2 + nnz3 + nnz4 + nnz5;
        scatter_all<<<dim3((ntot + 255) / 256), dim3(256), 0, stream>>>(
            idx2, val2, nnz2, idx3, val3, nnz3, idx4, val4, nnz4, idx5, val5, nnz5,
            W2, W3, W4, W5);
    }

    // 5) layer 1: MFMA GEMM, split-K = 30, XCD-aware + counted-vmcnt pipeline
    gemm1<<<dim3(8 * 75), dim3(256), 0, stream>>>(Xb, W1, y1);

    // 6) BN1 + silu (b1 cancels inside BN)
    bn_silu<<<dim3(N1P / 64), dim3(512), 0, stream>>>(y1, N1P, 600, g1, be1, h1);

    // 7) layer 2: silu(h1 @ W2^T + b2)
    small_gemm<1, 0><<<dim3(8, N2P / 64), dim3(256), 0, stream>>>(h1, N1P, W2, 640, b2, 600,
                                                                  h2, N2P, N2P, 640);
    // 8) layer 3 + BN2 + silu (b3 cancels)
    small_gemm<0, 0><<<dim3(8, N3P / 64), dim3(256), 0, stream>>>(h2, N2P, W3, 640, nullptr, 0,
                                                                  y3, N3P, N3P, 640);
    bn_silu<<<dim3(N3P / 64), dim3(512), 0, stream>>>(y3, N3P, 300, g2, be2, h3);

    // 9) layer 4 + BN3 + silu (b4 cancels)
    small_gemm<0, 0><<<dim3(8, N4P / 64), dim3(256), 0, stream>>>(h3, N3P, W4, 320, nullptr, 0,
                                                                  y4, N4P, N4P, 320);
    bn_silu<<<dim3(N4P / 64), dim3(512), 0, stream>>>(y4, N4P, 200, g3, be3, h4);

    // 10) layer 5: h4 @ W5^T + b5 -> d_out (fp32, compact 512x200)
    small_gemm<0, 1><<<dim3(8, N5P / 64), dim3(256), 0, stream>>>(h4, N4P, W5, 256, b5, 200,
                                                                  (float*)d_out, 200, 200, 256);
    (void)n_in; (void)out_size; (void)ws_size;
}

// Round 8
// 1033.081 us; speedup vs baseline: 1.1149x; 1.0048x over previous
//
#include <hip/hip_runtime.h>

typedef unsigned short ushort_t;
typedef unsigned int uint_t;

typedef __bf16 bf16x8 __attribute__((ext_vector_type(8)));
typedef float  floatx4 __attribute__((ext_vector_type(4)));

#define AS3 __attribute__((address_space(3)))
#define AS1 __attribute__((address_space(1)))

// ---------------- dims ----------------
#define BATCH 512
#define D_IN  120000
#define N1P   640   // 600 padded to 5*128
#define N2P   640
#define N3P   320
#define N4P   256
#define N5P   256

// gemm1 split-K: 30 chunks of 4000 (125 iters of BK=32); grid 600 = 8 XCDs * 75
#define KSPLIT 30
#define KCHUNK 4000

// ---------------- layer-1 partition params ----------------
#define HALF    60000
#define CHW     15000          // build accumulator width (4 phases per half)
#define NREG    1200
#define NB      256            // partition blocks
#define RSTRIDE 6912           // slab slots per region: mean 6000, +11 sigma

// ---------------- workspace layout ----------------
static constexpr long O_W1 = 0;                          // bf16 [640][120000]
static constexpr long SZ_W1 = 640L * 120000 * 2;
static constexpr long O_W2 = O_W1 + SZ_W1;               // f32 [640][640]
static constexpr long SZ_W2 = 640L * 640 * 4;
static constexpr long O_W3 = O_W2 + SZ_W2;               // f32 [320][640]
static constexpr long SZ_W3 = 320L * 640 * 4;
static constexpr long O_W4 = O_W3 + SZ_W3;               // f32 [256][320]
static constexpr long SZ_W4 = 256L * 320 * 4;
static constexpr long O_W5 = O_W4 + SZ_W4;               // f32 [256][256]
static constexpr long SZ_W5 = 256L * 256 * 4;
static constexpr long O_Y1 = O_W5 + SZ_W5;               // f32 [512][640] split-K target
static constexpr long SZ_Y1 = 512L * 640 * 4;
static constexpr long ZERO_OFF = O_W2;                   // zero W2..W5 + y1
static constexpr long ZERO_BYTES = (O_Y1 + SZ_Y1) - O_W2;
static constexpr long O_SCR = O_Y1 + SZ_Y1;              // scratch (partition, then h bufs)
// partition arrays (live only until build_w1 completes)
static constexpr long O_CNT = O_SCR;                         // int [NREG][NB]
static constexpr long O_OFF = O_CNT + (long)NREG * NB * 4;   // int [NB][NREG]
static constexpr long O_TOT = O_OFF + (long)NB * NREG * 4;   // int [NREG]
static constexpr long O_REC = O_TOT + 4800;                  // int2 [NREG][RSTRIDE] = 66.4 MB
// h-buffers alias the same scratch (partition dead before bn_silu writes h1)
static constexpr long O_H1 = O_SCR;                      // f32 [512][640]
static constexpr long O_H2 = O_H1 + 512L * 640 * 4;      // f32 [512][640]
static constexpr long O_Y3 = O_H2 + 512L * 640 * 4;      // f32 [512][320]
static constexpr long O_H3 = O_Y3 + 512L * 320 * 4;      // f32 [512][320]
static constexpr long O_Y4 = O_H3 + 512L * 320 * 4;      // f32 [512][256]
static constexpr long O_H4 = O_Y4 + 512L * 256 * 4;      // f32 [512][256]

// ---------------- helpers ----------------
__device__ __forceinline__ ushort_t f2bf(float f) {
    union { float f; uint_t u; } x;
    x.f = f;
    uint_t u = x.u;
    return (ushort_t)((u + 0x7FFFu + ((u >> 16) & 1u)) >> 16);  // RNE
}
__device__ __forceinline__ uint_t cvt_pk_bf16(float lo, float hi) {
    uint_t r;
    asm("v_cvt_pk_bf16_f32 %0, %1, %2" : "=v"(r) : "v"(lo), "v"(hi));  // RNE pack
    return r;
}
__device__ __forceinline__ float silu_f(float z) {
    return z / (1.f + expf(-z));
}
__device__ __forceinline__ void load16_lds(const void* g, void* l) {
    __builtin_amdgcn_global_load_lds((const AS1 char*)g, (AS3 char*)l, 16, 0, 0);
}

// ---------------- zero workspace (small region only) ----------------
__global__ void zero_f4(float4* __restrict__ p, long n4) {
    long stride = (long)gridDim.x * blockDim.x;
    for (long i = (long)blockIdx.x * blockDim.x + threadIdx.x; i < n4; i += stride)
        p[i] = make_float4(0.f, 0.f, 0.f, 0.f);
}

// ---------------- layer-1 pass A: per-block region histogram (LDS only) ----------------
__global__ __launch_bounds__(512) void hist1(const int* __restrict__ idx, int nnz, int chunk,
                                             int* __restrict__ counts /*[NREG][NB]*/) {
    __shared__ uint_t h[NREG];
    const int b = blockIdx.x, t = threadIdx.x;
    for (int i = t; i < NREG; i += 512) h[i] = 0;
    __syncthreads();
    const int s = b * chunk;
    const int e = min(s + chunk, nnz);
    for (int i = s + t; i < e; i += 512) {
        int r = idx[i];
        int c = idx[nnz + i];
        atomicAdd(&h[r * 2 + (c >= HALF ? 1 : 0)], 1u);
    }
    __syncthreads();
    for (int i = t; i < NREG; i += 512) counts[(long)i * NB + b] = (int)h[i];
}

// ---------------- layer-1 pass B: per-region exclusive scan over block counts ----------------
__global__ __launch_bounds__(NB) void scan1(const int* __restrict__ counts /*[NREG][NB]*/,
                                            int* __restrict__ offs /*[NB][NREG]*/,
                                            int* __restrict__ totals) {
    __shared__ int s[NB];
    const int reg = blockIdx.x, t = threadIdx.x;
    const int v = counts[(long)reg * NB + t];
    s[t] = v;
    __syncthreads();
    for (int o = 1; o < NB; o <<= 1) {
        int x = (t >= o) ? s[t - o] : 0;
        __syncthreads();
        s[t] += x;
        __syncthreads();
    }
    offs[(long)t * NREG + reg] = s[t] - v;  // exclusive prefix
    if (t == NB - 1) totals[reg] = s[t];
}

// ---------------- layer-1 pass C: scatter records into block-private spans ----------------
__global__ __launch_bounds__(512) void scatter1(const int* __restrict__ idx,
                                                const float* __restrict__ vals,
                                                int nnz, int chunk,
                                                const int* __restrict__ offs /*[NB][NREG]*/,
                                                int2* __restrict__ rec) {
    __shared__ int cur[NREG];
    const int b = blockIdx.x, t = threadIdx.x;
    const int* ob = offs + (long)b * NREG;
    for (int i = t; i < NREG; i += 512) cur[i] = i * RSTRIDE + ob[i];
    __syncthreads();
    const int s = b * chunk;
    const int e = min(s + chunk, nnz);
    for (int i = s + t; i < e; i += 512) {
        int r = idx[i];
        int c = idx[nnz + i];
        float v = vals[i];
        int h = (c >= HALF) ? 1 : 0;
        int reg = r * 2 + h;
        int slot = atomicAdd(&cur[reg], 1);  // LDS atomic -> private global slot
        if (slot < (reg + 1) * RSTRIDE)
            rec[slot] = make_int2(c - h * HALF, __float_as_int(v));
    }
}

// ---------------- layer-1 pass D: LDS f32 accumulate, single bf16 writeout ----------------
__global__ __launch_bounds__(512) void build_w1(const int2* __restrict__ rec,
                                                const int* __restrict__ totals,
                                                ushort_t* __restrict__ W) {
    const int bid = blockIdx.x;
    const int r = bid >> 1, h = bid & 1;
    const int t = threadIdx.x;
    ushort_t* dstbase = W + (size_t)r * D_IN + h * HALF;

    if (r >= 600) {  // padding rows: stream zeros
        uint4 z = make_uint4(0, 0, 0, 0);
        for (int j = t * 8; j < HALF; j += 512 * 8) *(uint4*)(dstbase + j) = z;
        return;
    }

    __shared__ int2 lrec[RSTRIDE];  // 55,296 B
    __shared__ float acc[CHW];      // 60,000 B

    const int reg = r * 2 + h;
    const int n = min(totals[reg], RSTRIDE);
    const int2* src = rec + (long)reg * RSTRIDE;
    for (int i = t; i < n; i += 512) lrec[i] = src[i];
    __syncthreads();

#pragma unroll
    for (int ch = 0; ch < 4; ch++) {
        for (int j = t * 4; j < CHW; j += 512 * 4)
            *(float4*)&acc[j] = make_float4(0.f, 0.f, 0.f, 0.f);
        __syncthreads();
        const int base = ch * CHW;
        for (int i = t; i < n; i += 512) {
            int2 e = lrec[i];
            unsigned off = (unsigned)(e.x - base);
            if (off < (unsigned)CHW)
                atomicAdd(&acc[off], __int_as_float(e.y));  // ds_add_f32
        }
        __syncthreads();
        ushort_t* dst = dstbase + base;
        for (int j = t * 8; j < CHW; j += 512 * 8) {
            union { ushort_t us[8]; uint4 v; } u;
#pragma unroll
            for (int k = 0; k < 8; k++) u.us[k] = f2bf(acc[j + k]);
            *(uint4*)(dst + j) = u.v;
        }
        __syncthreads();
    }
}

// ---------------- merged scatter for W2..W5 (one launch) ----------------
__global__ void scatter_all(const int* __restrict__ i2, const float* __restrict__ v2, int n2,
                            const int* __restrict__ i3, const float* __restrict__ v3, int n3,
                            const int* __restrict__ i4, const float* __restrict__ v4, int n4,
                            const int* __restrict__ i5, const float* __restrict__ v5, int n5,
                            float* __restrict__ W2, float* __restrict__ W3,
                            float* __restrict__ W4, float* __restrict__ W5) {
    int i = blockIdx.x * blockDim.x + threadIdx.x;
    if (i < n2) { atomicAdd(&W2[(size_t)i2[i] * 640 + i2[n2 + i]], v2[i]); return; }
    i -= n2;
    if (i < n3) { atomicAdd(&W3[(size_t)i3[i] * 640 + i3[n3 + i]], v3[i]); return; }
    i -= n3;
    if (i < n4) { atomicAdd(&W4[(size_t)i4[i] * 320 + i4[n4 + i]], v4[i]); return; }
    i -= n4;
    if (i < n5) { atomicAdd(&W5[(size_t)i5[i] * 256 + i5[n5 + i]], v5[i]); }
}

// ---------------- GEMM1: y1(512x640,f32) += X(512x120000,f32 -> bf16 in-kernel) @ W1^T ----
// Fused-cast rev 2 (R4 retry, now safe post-XCD-mapping): B staged via global_load_lds;
// A loaded f32 -> regs -> cvt_pk_bf16 -> ds_write ONE ITERATION LATER (its loads are the
// oldest outstanding VM ops, so the compiler's value-wait leaves this iter's 6 new ops in
// flight). Explicit vmcnt(6) + lgkmcnt(0) before each raw s_barrier; never vmcnt(0) in
// the main loop. 3 LDS buffer rotation (cb/wb/nb), 48 KB -> 3 blocks/CU. XCD-aware decode
// (FETCH 942->153 MB in R5); source-side XOR swizzle (0 bank conflicts R4-R7).
__global__ __launch_bounds__(256) void gemm1(const float* __restrict__ X,
                                             const ushort_t* __restrict__ W,
                                             float* __restrict__ Y) {
    __shared__ ushort_t sA[3][4096];   // 3 x 8 KB
    __shared__ ushort_t sB[3][4096];

    const int b = blockIdx.x;
    const int wrk = (b & 7) * 75 + (b >> 3);    // contiguous per XCD (600 = 8*75)
    const int ksIdx = wrk / 20;
    const int tile = wrk % 20;
    const int bm = tile / 5, bn = tile % 5;
    const int ks = ksIdx * KCHUNK;
    const int iters = KCHUNK / 32;  // 125

    const int t = threadIdx.x;
    const int lane = t & 63;
    const int w = t >> 6;
    const int wm = w >> 1, wn = w & 1;
    const int i16 = lane & 15;
    const int qk = lane >> 4;

    // staging: thread t owns chunks t and t+256; chunk c (16B at LDS byte c*16) holds
    // (row = c>>2, k-quad = (c&3)^((c>>3)&3)) -> source address carries the swizzle.
    const int row0 = t >> 2;
    const int kq = (t & 3) ^ ((t >> 3) & 3);

    const float*    qa0 = X + (size_t)(bm * 128 + row0) * D_IN + ks + kq * 8;
    const float*    qa1 = qa0 + (size_t)64 * D_IN;
    const ushort_t* pb0 = W + (size_t)(bn * 128 + row0) * D_IN + ks + kq * 8;
    const ushort_t* pb1 = pb0 + (size_t)64 * D_IN;

    int aoff[4], boff[4];
#pragma unroll
    for (int mi = 0; mi < 4; mi++) {
        int row = wm * 64 + mi * 16 + i16;
        aoff[mi] = row * 64 + ((qk ^ ((row >> 1) & 3)) * 16);
    }
#pragma unroll
    for (int ni = 0; ni < 4; ni++) {
        int row = wn * 64 + ni * 16 + i16;
        boff[ni] = row * 64 + ((qk ^ ((row >> 1) & 3)) * 16);
    }
    const char* sAb = (const char*)sA;
    const char* sBb = (const char*)sB;

#define STAGEB(s) do {                                   \
        load16_lds(pb0, &sB[s][(w * 64) * 8]);           \
        load16_lds(pb1, &sB[s][(256 + w * 64) * 8]);     \
        pb0 += 32; pb1 += 32; } while (0)
#define LOADA(d0, d1, d2, d3) do {                       \
        d0 = *(const float4*)qa0;                        \
        d1 = *(const float4*)(qa0 + 4);                  \
        d2 = *(const float4*)qa1;                        \
        d3 = *(const float4*)(qa1 + 4);                  \
        qa0 += 32; qa1 += 32; } while (0)
#define WRITEA(s, d0, d1, d2, d3) do {                   \
        uint4 u0, u1;                                    \
        u0.x = cvt_pk_bf16(d0.x, d0.y); u0.y = cvt_pk_bf16(d0.z, d0.w); \
        u0.z = cvt_pk_bf16(d1.x, d1.y); u0.w = cvt_pk_bf16(d1.z, d1.w); \
        u1.x = cvt_pk_bf16(d2.x, d2.y); u1.y = cvt_pk_bf16(d2.z, d2.w); \
        u1.z = cvt_pk_bf16(d3.x, d3.y); u1.w = cvt_pk_bf16(d3.z, d3.w); \
        *(uint4*)&sA[s][t * 8] = u0;                     \
        *(uint4*)&sA[s][(t + 256) * 8] = u1; } while (0)

    floatx4 acc[4][4] = {};
    float4 p0, p1, p2, p3;   // A(it+1) values, pending conversion
    float4 n0, n1, n2, n3;   // A(it+2) values, in flight

    // prologue: stage B(0),A(0),B(1),A(1); convert A(0) into buf 0
    {
        float4 a0, a1, a2, a3;
        STAGEB(0);
        LOADA(a0, a1, a2, a3);
        STAGEB(1);
        LOADA(p0, p1, p2, p3);
        asm volatile("s_waitcnt vmcnt(6)" ::: "memory");  // B(0)+A(0) done; B(1)+A(1) in flight
        WRITEA(0, a0, a1, a2, a3);
        asm volatile("s_waitcnt lgkmcnt(0)" ::: "memory");
    }
    __builtin_amdgcn_s_barrier();
    __builtin_amdgcn_sched_barrier(0);

    int cb = 0, wb = 1, nb = 2;
    for (int it = 0; it < iters; ++it) {
        if (it + 2 < iters) {          // issue stage(it+2): B -> LDS, A -> regs
            STAGEB(nb);
            LOADA(n0, n1, n2, n3);
        }

        const int cbo = cb * 8192;
        bf16x8 af[4], bfr[4];
#pragma unroll
        for (int mi = 0; mi < 4; mi++)
            af[mi] = *(const bf16x8*)(sAb + cbo + aoff[mi]);
#pragma unroll
        for (int ni = 0; ni < 4; ni++)
            bfr[ni] = *(const bf16x8*)(sBb + cbo + boff[ni]);
#pragma unroll
        for (int mi = 0; mi < 4; mi++)
#pragma unroll
            for (int ni = 0; ni < 4; ni++)
                acc[mi][ni] = __builtin_amdgcn_mfma_f32_16x16x32_bf16(af[mi], bfr[ni], acc[mi][ni], 0, 0, 0);

        if (it + 1 < iters) {
            // p-values are the OLDEST outstanding VM ops -> their wait leaves the
            // 6 ops issued this iteration in flight (compiler computes vmcnt(6)).
            WRITEA(wb, p0, p1, p2, p3);
            p0 = n0; p1 = n1; p2 = n2; p3 = n3;
            // explicit floor: drain everything older than this iter's 6 issues
            // (guards against scheduler reordering A/B issue order)
            asm volatile("s_waitcnt vmcnt(6)" ::: "memory");
            asm volatile("s_waitcnt lgkmcnt(0)" ::: "memory");
            __builtin_amdgcn_s_barrier();
            __builtin_amdgcn_sched_barrier(0);
        }
        int tmp = cb; cb = wb; wb = nb; nb = tmp;   // rotate buffers
    }
#undef STAGEB
#undef LOADA
#undef WRITEA

    // epilogue: split-K atomic accumulate (C/D: col = lane&15, row = (lane>>4)*4 + reg)
#pragma unroll
    for (int mi = 0; mi < 4; mi++) {
#pragma unroll
        for (int ni = 0; ni < 4; ni++) {
#pragma unroll
            for (int r = 0; r < 4; r++) {
                int row = bm * 128 + wm * 64 + mi * 16 + qk * 4 + r;
                int col = bn * 128 + wn * 64 + ni * 16 + i16;
                atomicAdd(&Y[(size_t)row * N1P + col], acc[mi][ni][r]);
            }
        }
    }
}

// ---------------- BatchNorm (training, biased var) + SiLU, coalesced 64-col tiles --------
__global__ __launch_bounds__(512) void bn_silu(const float* __restrict__ Y, int ld, int realN,
                                               const float* __restrict__ g,
                                               const float* __restrict__ be,
                                               float* __restrict__ H) {
    const int t = threadIdx.x;
    const int sub = t >> 6;          // 0..7
    const int c = t & 63;
    const int col = blockIdx.x * 64 + c;

    float s = 0.f, ss = 0.f;
#pragma unroll 8
    for (int r = sub; r < BATCH; r += 8) {
        float v = Y[(size_t)r * ld + col];
        s += v;
        ss += v * v;
    }
    __shared__ float rs[8][64], rq[8][64], scs[64], shs[64];
    rs[sub][c] = s;
    rq[sub][c] = ss;
    __syncthreads();
    if (t < 64) {
        float S = 0.f, SS = 0.f;
#pragma unroll
        for (int k = 0; k < 8; k++) { S += rs[k][t]; SS += rq[k][t]; }
        float mean = S * (1.f / 512.f);
        float var  = SS * (1.f / 512.f) - mean * mean;
        int cc = blockIdx.x * 64 + t;
        float sc = 0.f, sh = 0.f;
        if (cc < realN) {
            sc = rsqrtf(var + 1e-5f) * g[cc];
            sh = be[cc] - mean * sc;
        }
        scs[t] = sc;
        shs[t] = sh;
    }
    __syncthreads();
    const float sc = scs[c], sh = shs[c];
#pragma unroll 8
    for (int r = sub; r < BATCH; r += 8) {
        float v = Y[(size_t)r * ld + col];
        H[(size_t)r * ld + col] = silu_f(v * sc + sh);  // pad cols -> silu(0)=0
    }
}

// ---------------- small fp32 GEMM: C(512 x N) = A(512 x K) @ W^T(N x K) ----------------
template <int ACT, int GUARD>
__global__ __launch_bounds__(256) void small_gemm(const float* __restrict__ A, int lda,
                                                  const float* __restrict__ W, int ldw,
                                                  const float* __restrict__ bias, int biasN,
                                                  float* __restrict__ out, int ldo, int outN,
                                                  int K) {
    __shared__ float sA[64][20];
    __shared__ float sB[64][20];
    const int t = threadIdx.x;
    const int m0 = blockIdx.x * 64, n0 = blockIdx.y * 64;
    const int ty = t >> 4, tx = t & 15;
    const int lm = t >> 2, lq = t & 3;
    float acc[4][4] = {};

    for (int kt = 0; kt < K; kt += 16) {
        __syncthreads();
        float4 av = *(const float4*)&A[(size_t)(m0 + lm) * lda + kt + lq * 4];
        float4 wv = *(const float4*)&W[(size_t)(n0 + lm) * ldw + kt + lq * 4];
        sA[lm][lq * 4 + 0] = av.x; sA[lm][lq * 4 + 1] = av.y;
        sA[lm][lq * 4 + 2] = av.z; sA[lm][lq * 4 + 3] = av.w;
        sB[lm][lq * 4 + 0] = wv.x; sB[lm][lq * 4 + 1] = wv.y;
        sB[lm][lq * 4 + 2] = wv.z; sB[lm][lq * 4 + 3] = wv.w;
        __syncthreads();
#pragma unroll
        for (int kg = 0; kg < 4; kg++) {
            float4 a4[4], b4[4];
#pragma unroll
            for (int i = 0; i < 4; i++) a4[i] = *(const float4*)&sA[ty * 4 + i][kg * 4];
#pragma unroll
            for (int j = 0; j < 4; j++) b4[j] = *(const float4*)&sB[tx * 4 + j][kg * 4];
#pragma unroll
            for (int i = 0; i < 4; i++)
#pragma unroll
                for (int j = 0; j < 4; j++)
                    acc[i][j] += a4[i].x * b4[j].x + a4[i].y * b4[j].y +
                                 a4[i].z * b4[j].z + a4[i].w * b4[j].w;
        }
    }

#pragma unroll
    for (int i = 0; i < 4; i++) {
#pragma unroll
        for (int j = 0; j < 4; j++) {
            int row = m0 + ty * 4 + i;
            int col = n0 + tx * 4 + j;
            float v = acc[i][j];
            if (bias != nullptr && col < biasN) v += bias[col];
            if (ACT == 1) v = silu_f(v);
            if (GUARD) {
                if (col < outN) out[(size_t)row * ldo + col] = v;
            } else {
                out[(size_t)row * ldo + col] = v;
            }
        }
    }
}

// ---------------- launch ----------------
extern "C" void kernel_launch(void* const* d_in, const int* in_sizes, int n_in,
                              void* d_out, int out_size, void* d_ws, size_t ws_size,
                              hipStream_t stream) {
    const float* x   = (const float*)d_in[0];
    const int* idx1 = (const int*)d_in[1];  const float* val1 = (const float*)d_in[2];
    const int* idx2 = (const int*)d_in[4];  const float* val2 = (const float*)d_in[5];
    const float* b2 = (const float*)d_in[6];
    const int* idx3 = (const int*)d_in[7];  const float* val3 = (const float*)d_in[8];
    const int* idx4 = (const int*)d_in[10]; const float* val4 = (const float*)d_in[11];
    const int* idx5 = (const int*)d_in[13]; const float* val5 = (const float*)d_in[14];
    const float* b5 = (const float*)d_in[15];
    const float* g1 = (const float*)d_in[16]; const float* be1 = (const float*)d_in[17];
    const float* g2 = (const float*)d_in[18]; const float* be2 = (const float*)d_in[19];
    const float* g3 = (const float*)d_in[20]; const float* be3 = (const float*)d_in[21];

    const int nnz1 = in_sizes[1] / 2;
    const int nnz2 = in_sizes[4] / 2;
    const int nnz3 = in_sizes[7] / 2;
    const int nnz4 = in_sizes[10] / 2;
    const int nnz5 = in_sizes[13] / 2;

    char* ws = (char*)d_ws;
    ushort_t* W1 = (ushort_t*)(ws + O_W1);
    float* W2 = (float*)(ws + O_W2);
    float* W3 = (float*)(ws + O_W3);
    float* W4 = (float*)(ws + O_W4);
    float* W5 = (float*)(ws + O_W5);
    float* y1 = (float*)(ws + O_Y1);
    int*   cnt = (int*)(ws + O_CNT);
    int*   off = (int*)(ws + O_OFF);
    int*   tot = (int*)(ws + O_TOT);
    int2*  rec = (int2*)(ws + O_REC);
    float* h1 = (float*)(ws + O_H1);
    float* h2 = (float*)(ws + O_H2);
    float* y3 = (float*)(ws + O_Y3);
    float* h3 = (float*)(ws + O_H3);
    float* y4 = (float*)(ws + O_Y4);
    float* h4 = (float*)(ws + O_H4);

    // 1) zero W2..W5 + y1 (4.4 MB; W1 not pre-zeroed)
    zero_f4<<<dim3((unsigned)(ZERO_BYTES / 16 / 256 + 1)), dim3(256), 0, stream>>>(
        (float4*)(ws + ZERO_OFF), ZERO_BYTES / 16);

    // 2) layer-1 partition: histogram -> scan -> block-private scatter -> build
    {
        const int chunk = (nnz1 + NB - 1) / NB;
        hist1<<<dim3(NB), dim3(512), 0, stream>>>(idx1, nnz1, chunk, cnt);
        scan1<<<dim3(NREG), dim3(NB), 0, stream>>>(cnt, off, tot);
        scatter1<<<dim3(NB), dim3(512), 0, stream>>>(idx1, val1, nnz1, chunk, off, rec);
        build_w1<<<dim3(640 * 2), dim3(512), 0, stream>>>(rec, tot, W1);
    }

    // 3) densify small weights (one launch)
    {
        int ntot = nnz2 + nnz3 + nnz4 + nnz5;
        scatter_all<<<dim3((ntot + 255) / 256), dim3(256), 0, stream>>>(
            idx2, val2, nnz2, idx3, val3, nnz3, idx4, val4, nnz4, idx5, val5, nnz5,
            W2, W3, W4, W5);
    }

    // 4) layer 1: fused-cast MFMA GEMM, split-K = 30, XCD-aware + counted-vmcnt pipeline
    gemm1<<<dim3(8 * 75), dim3(256), 0, stream>>>(x, W1, y1);

    // 5) BN1 + silu (b1 cancels inside BN)
    bn_silu<<<dim3(N1P / 64), dim3(512), 0, stream>>>(y1, N1P, 600, g1, be1, h1);

    // 6) layer 2: silu(h1 @ W2^T + b2)
    small_gemm<1, 0><<<dim3(8, N2P / 64), dim3(256), 0, stream>>>(h1, N1P, W2, 640, b2, 600,
                                                                  h2, N2P, N2P, 640);
    // 7) layer 3 + BN2 + silu (b3 cancels)
    small_gemm<0, 0><<<dim3(8, N3P / 64), dim3(256), 0, stream>>>(h2, N2P, W3, 640, nullptr, 0,
                                                                  y3, N3P, N3P, 640);
    bn_silu<<<dim3(N3P / 64), dim3(512), 0, stream>>>(y3, N3P, 300, g2, be2, h3);

    // 8) layer 4 + BN3 + silu (b4 cancels)
    small_gemm<0, 0><<<dim3(8, N4P / 64), dim3(256), 0, stream>>>(h3, N3P, W4, 320, nullptr, 0,
                                                                  y4, N4P, N4P, 320);
    bn_silu<<<dim3(N4P / 64), dim3(512), 0, stream>>>(y4, N4P, 200, g3, be3, h4);

    // 9) layer 5: h4 @ W5^T + b5 -> d_out (fp32, compact 512x200)
    small_gemm<0, 1><<<dim3(8, N5P / 64), dim3(256), 0, stream>>>(h4, N4P, W5, 256, b5, 200,
                                                                  (float*)d_out, 200, 200, 256);
    (void)n_in; (void)out_size; (void)ws_size;
}